// Round 1
// baseline (64.730 us; speedup 1.0000x reference)
//
#include <hip/hip_runtime.h>
#include <math.h>

#define VOX 32768
#define DD 512
#define KC 32
#define NQ 524288
#define EPSF 1e-8f

// ws float layout:
// [0..512)      featsum (pre-bias, pre-relu accumulator of voxel @ W_enc)
// [512..1024)   decsum  (pre-bias accumulator of feat @ W_dec)
// [1024..1280)  mapsum  (pre-bias accumulator of dec @ W_map)
// [1280..1664)  cone derived params, 32 cones x 12 floats
#define WS_FEAT 0
#define WS_DEC  512
#define WS_MAP  1024
#define WS_CONE 1280

__device__ __constant__ float c_mult[8]  = {1.f, 1.f, 1.f, 0.01f, 0.03f, 1.7f, 1.7f, 1.7f};
__device__ __constant__ float c_adder[8] = {-0.8f, -0.8f, -0.8f, 0.05f, 0.1f, -1.f, -1.f, -1.f};

// Stage 1: featsum[d] += sum_v voxel[v] * W_enc[v*512 + d]
// 512 blocks x 512 threads; each block handles 64 rows of W_enc.
// Threads: 4 row-groups x 128 col-threads, float4 per col-thread.
__global__ __launch_bounds__(512) void k_enc(const float* __restrict__ vox,
                                             const float* __restrict__ Wenc,
                                             float* __restrict__ featsum) {
    __shared__ float4 red4[512];
    const int t  = threadIdx.x;
    const int g  = t >> 7;          // row group 0..3
    const int c4 = (t & 127) << 2;  // starting column
    const int v0 = blockIdx.x * 64;
    float4 acc = make_float4(0.f, 0.f, 0.f, 0.f);
    #pragma unroll
    for (int it = 0; it < 16; ++it) {
        const int v = v0 + it * 4 + g;
        const float sv = vox[v];
        const float4 w = *reinterpret_cast<const float4*>(&Wenc[(size_t)v * DD + c4]);
        acc.x += sv * w.x; acc.y += sv * w.y; acc.z += sv * w.z; acc.w += sv * w.w;
    }
    red4[t] = acc;   // red[g*512 + column] when viewed as floats
    __syncthreads();
    const float* red = reinterpret_cast<const float*>(red4);
    const int d = t;
    float s = red[d] + red[512 + d] + red[1024 + d] + red[1536 + d];
    atomicAdd(&featsum[d], s);
}

// Stage 2: decsum[d] += sum_i relu(featsum[i]+b_enc[i]) * W_dec[i*512+d]
// 128 blocks x 512 threads; each block handles 4 rows.
__global__ __launch_bounds__(512) void k_dec(const float* __restrict__ featsum,
                                             const float* __restrict__ benc,
                                             const float* __restrict__ Wdec,
                                             float* __restrict__ decsum) {
    __shared__ float4 red4[512];
    const int t  = threadIdx.x;
    const int g  = t >> 7;
    const int c4 = (t & 127) << 2;
    const int i  = blockIdx.x * 4 + g;
    float fi = featsum[i] + benc[i];
    fi = fi > 0.f ? fi : 0.f;
    const float4 w = *reinterpret_cast<const float4*>(&Wdec[(size_t)i * DD + c4]);
    red4[t] = make_float4(fi * w.x, fi * w.y, fi * w.z, fi * w.w);
    __syncthreads();
    const float* red = reinterpret_cast<const float*>(red4);
    const int d = t;
    float s = red[d] + red[512 + d] + red[1024 + d] + red[1536 + d];
    atomicAdd(&decsum[d], s);
}

// Stage 3: mapsum[j] += sum_i relu(decsum[i]+b_dec[i]) * W_map[i*256+j]
// 64 blocks x 256 threads; each block handles 8 rows.
__global__ __launch_bounds__(256) void k_map(const float* __restrict__ decsum,
                                             const float* __restrict__ bdec,
                                             const float* __restrict__ Wmap,
                                             float* __restrict__ mapsum) {
    const int j  = threadIdx.x;
    const int i0 = blockIdx.x * 8;
    float acc = 0.f;
    #pragma unroll
    for (int r = 0; r < 8; ++r) {
        const int i = i0 + r;
        float di = decsum[i] + bdec[i];
        di = di > 0.f ? di : 0.f;
        acc += di * Wmap[(size_t)i * 256 + j];
    }
    atomicAdd(&mapsum[j], acc);
}

// Stage 4: finalize cone params: sigmoid*mult+adder, write to d_out tail,
// and precompute derived per-cone values for the SDF kernel.
__global__ __launch_bounds__(256) void k_params(const float* __restrict__ mapsum,
                                                const float* __restrict__ bmap,
                                                float* __restrict__ out_params,
                                                float* __restrict__ cones) {
    __shared__ float p[256];
    const int j = threadIdx.x;
    const float s = mapsum[j] + bmap[j];
    const float sig = 1.f / (1.f + expf(-s));
    const float val = sig * c_mult[j & 7] + c_adder[j & 7];
    out_params[j] = val;
    p[j] = val;
    __syncthreads();
    if (j < KC) {
        const float cx = p[j*8+0], cy = p[j*8+1], cz = p[j*8+2];
        const float r  = p[j*8+3], h  = p[j*8+4];
        const float ox = p[j*8+5], oy = p[j*8+6], oz = p[j*8+7];
        const float nrm = sqrtf(ox*ox + oy*oy + oz*oz) + EPSF;
        const float inv = 1.f / nrm;
        const float ax = ox*inv, ay = oy*inv, az = oz*inv;
        const float inv_h = 1.f / (h + EPSF);
        float* ck = &cones[j * 12];
        ck[0] = cx; ck[1] = cy; ck[2] = cz;
        ck[3] = ax; ck[4] = ay; ck[5] = az;
        ck[6] = r;  ck[7] = h;  ck[8] = inv_h; ck[9] = r * inv_h;
        ck[10] = 0.f; ck[11] = 0.f;
    }
}

// Stage 5: the big SDF eval. One thread per query, 32 cones each,
// 8 x float4 coalesced write (128B per thread).
__global__ __launch_bounds__(256) void k_sdf(const float* __restrict__ q,
                                             const float* __restrict__ cones,
                                             float* __restrict__ out) {
    __shared__ float c[KC * 12];
    const int t = threadIdx.x;
    c[t] = cones[t];
    if (t < KC * 12 - 256) c[256 + t] = cones[256 + t];
    __syncthreads();
    const int n = blockIdx.x * 256 + t;
    const float qx = q[(size_t)n * 3 + 0];
    const float qy = q[(size_t)n * 3 + 1];
    const float qz = q[(size_t)n * 3 + 2];
    float4 o[8];
    float* of = reinterpret_cast<float*>(o);
    #pragma unroll
    for (int k = 0; k < KC; ++k) {
        const float* ck = &c[k * 12];
        const float vx = qx - ck[0];
        const float vy = qy - ck[1];
        const float vz = qz - ck[2];
        const float proj = vx * ck[3] + vy * ck[4] + vz * ck[5];
        const float d2 = vx * vx + vy * vy + vz * vz;
        float pp = d2 - proj * proj;
        pp = pp > 0.f ? pp : 0.f;
        const float perp = sqrtf(pp);
        const float slant = perp - ck[6] + ck[9] * proj;
        const float cap = fabsf(proj) - ck[7];
        of[k] = slant > cap ? slant : cap;
    }
    float4* ob = reinterpret_cast<float4*>(&out[(size_t)n * KC]);
    #pragma unroll
    for (int w = 0; w < 8; ++w) ob[w] = o[w];
}

extern "C" void kernel_launch(void* const* d_in, const int* in_sizes, int n_in,
                              void* d_out, int out_size, void* d_ws, size_t ws_size,
                              hipStream_t stream) {
    const float* vox  = (const float*)d_in[0];
    const float* q    = (const float*)d_in[1];
    // d_in[2] = initial_centers: unused by the reference
    const float* Wenc = (const float*)d_in[3];
    const float* benc = (const float*)d_in[4];
    const float* Wdec = (const float*)d_in[5];
    const float* bdec = (const float*)d_in[6];
    const float* Wmap = (const float*)d_in[7];
    const float* bmap = (const float*)d_in[8];
    float* out = (float*)d_out;
    float* ws  = (float*)d_ws;

    // zero the three accumulator regions (1280 floats)
    hipMemsetAsync(ws, 0, (size_t)(512 + 512 + 256) * sizeof(float), stream);

    k_enc<<<512, 512, 0, stream>>>(vox, Wenc, ws + WS_FEAT);
    k_dec<<<128, 512, 0, stream>>>(ws + WS_FEAT, benc, Wdec, ws + WS_DEC);
    k_map<<<64, 256, 0, stream>>>(ws + WS_DEC, bdec, Wmap, ws + WS_MAP);
    k_params<<<1, 256, 0, stream>>>(ws + WS_MAP, bmap, out + (size_t)NQ * KC, ws + WS_CONE);
    k_sdf<<<NQ / 256, 256, 0, stream>>>(q, ws + WS_CONE, out);
}

// Round 2
// 49.397 us; speedup vs baseline: 1.3104x; 1.3104x over previous
//
#include <hip/hip_runtime.h>
#include <math.h>

#define VOX 32768
#define DD 512
#define KC 32
#define NQ 524288
#define EPSF 1e-8f
#define CONE_STRIDE 13   // padded from 12 -> conflict-free LDS reads in k_sdf

__device__ __constant__ float c_mult[8]  = {1.f, 1.f, 1.f, 0.01f, 0.03f, 1.7f, 1.7f, 1.7f};
__device__ __constant__ float c_adder[8] = {-0.8f, -0.8f, -0.8f, 0.05f, 0.1f, -1.f, -1.f, -1.f};

// Stage 1: per-block partial of featsum[d] = sum_v voxel[v]*W_enc[v*512+d]
// 512 blocks x 512 threads, block handles 64 rows, coalesced float4 reads.
// mode=1: store transposed partialT[d*512 + b]  (atomic-free)
// mode=0: atomicAdd into featsum[d]             (ws too small fallback)
// Block 0 additionally zeroes decsum+mapsum (768 floats at zbase).
__global__ __launch_bounds__(512) void k_enc(const float* __restrict__ vox,
                                             const float* __restrict__ Wenc,
                                             float* __restrict__ dst,
                                             float* __restrict__ zbase,
                                             int mode) {
    __shared__ float4 red4[512];
    const int t = threadIdx.x;
    const int b = blockIdx.x;
    if (b == 0) {
        zbase[t] = 0.f;
        if (t < 256) zbase[512 + t] = 0.f;
    }
    const int g  = t >> 7;          // row group 0..3
    const int c4 = (t & 127) << 2;  // starting column
    const int v0 = b * 64;
    float4 acc = make_float4(0.f, 0.f, 0.f, 0.f);
    #pragma unroll
    for (int it = 0; it < 16; ++it) {
        const int v = v0 + it * 4 + g;
        const float sv = vox[v];
        const float4 w = *reinterpret_cast<const float4*>(&Wenc[(size_t)v * DD + c4]);
        acc.x += sv * w.x; acc.y += sv * w.y; acc.z += sv * w.z; acc.w += sv * w.w;
    }
    red4[t] = acc;
    __syncthreads();
    const float* red = reinterpret_cast<const float*>(red4);
    const float s = red[t] + red[512 + t] + red[1024 + t] + red[1536 + t];
    if (mode) dst[(size_t)t * 512 + b] = s;   // partialT[d][b]
    else      atomicAdd(&dst[t], s);
}

// Stage 2: decsum[d] = sum_i relu(featsum[i]+b_enc[i]) * W_dec[i*512+d]
// 128 blocks x 512 threads (4 rows/block).
// mode=1: featsum row i reduced from partialT[i*512 + 0..512) (coalesced float4
//         + wave shuffle + 2-wave LDS combine). mode=0: read featsum directly.
__global__ __launch_bounds__(512) void k_dec(const float* __restrict__ src,
                                             const float* __restrict__ benc,
                                             const float* __restrict__ Wdec,
                                             float* __restrict__ decsum,
                                             int mode) {
    __shared__ float4 red4[512];
    __shared__ float wsum[8];
    const int t = threadIdx.x;
    const int g = t >> 7;       // row group 0..3
    const int j = t & 127;
    const int i = blockIdx.x * 4 + g;
    float f;
    if (mode) {
        const float4 pv = *reinterpret_cast<const float4*>(&src[(size_t)i * 512 + j * 4]);
        float s = pv.x + pv.y + pv.z + pv.w;
        #pragma unroll
        for (int off = 32; off >= 1; off >>= 1) s += __shfl_xor(s, off, 64);
        if ((t & 63) == 0) wsum[t >> 6] = s;
        __syncthreads();
        f = wsum[2 * g] + wsum[2 * g + 1];
    } else {
        f = src[i];
    }
    float fi = f + benc[i];
    fi = fi > 0.f ? fi : 0.f;
    const int c4 = j << 2;
    const float4 w = *reinterpret_cast<const float4*>(&Wdec[(size_t)i * DD + c4]);
    red4[t] = make_float4(fi * w.x, fi * w.y, fi * w.z, fi * w.w);
    __syncthreads();
    const float* red = reinterpret_cast<const float*>(red4);
    const float s2 = red[t] + red[512 + t] + red[1024 + t] + red[1536 + t];
    atomicAdd(&decsum[t], s2);
}

// Stage 3: mapsum[j] = sum_i relu(decsum[i]+b_dec[i]) * W_map[i*256+j]
__global__ __launch_bounds__(256) void k_map(const float* __restrict__ decsum,
                                             const float* __restrict__ bdec,
                                             const float* __restrict__ Wmap,
                                             float* __restrict__ mapsum) {
    const int j  = threadIdx.x;
    const int i0 = blockIdx.x * 8;
    float acc = 0.f;
    #pragma unroll
    for (int r = 0; r < 8; ++r) {
        const int i = i0 + r;
        float di = decsum[i] + bdec[i];
        di = di > 0.f ? di : 0.f;
        acc += di * Wmap[(size_t)i * 256 + j];
    }
    atomicAdd(&mapsum[j], acc);
}

// Stage 4: sigmoid*mult+adder -> out params tail + derived cone values.
__global__ __launch_bounds__(256) void k_params(const float* __restrict__ mapsum,
                                                const float* __restrict__ bmap,
                                                float* __restrict__ out_params,
                                                float* __restrict__ cones) {
    __shared__ float p[256];
    const int j = threadIdx.x;
    const float s = mapsum[j] + bmap[j];
    const float sig = 1.f / (1.f + expf(-s));
    const float val = sig * c_mult[j & 7] + c_adder[j & 7];
    out_params[j] = val;
    p[j] = val;
    __syncthreads();
    if (j < KC) {
        const float cx = p[j*8+0], cy = p[j*8+1], cz = p[j*8+2];
        const float r  = p[j*8+3], h  = p[j*8+4];
        const float ox = p[j*8+5], oy = p[j*8+6], oz = p[j*8+7];
        const float nrm = sqrtf(ox*ox + oy*oy + oz*oz) + EPSF;
        const float inv = 1.f / nrm;
        const float inv_h = 1.f / (h + EPSF);
        float* ck = &cones[j * CONE_STRIDE];
        ck[0] = cx;      ck[1] = cy;      ck[2] = cz;
        ck[3] = ox*inv;  ck[4] = oy*inv;  ck[5] = oz*inv;
        ck[6] = r;       ck[7] = h;       ck[8] = inv_h;
        ck[9] = r * inv_h; ck[10] = 0.f;  ck[11] = 0.f;  ck[12] = 0.f;
    }
}

// Stage 5: SDF eval, fully coalesced writes.
// Block = 256 threads handles 32 queries; thread t: query n0+(t>>3),
// cones (t&7)*4 .. +3 -> one float4 store, lane-consecutive 16B addresses.
__global__ __launch_bounds__(256) void k_sdf(const float* __restrict__ q,
                                             const float* __restrict__ cones,
                                             float* __restrict__ out) {
    __shared__ float sq[96];                 // 32 queries x 3
    __shared__ float c[KC * CONE_STRIDE];    // 416 floats
    const int t = threadIdx.x;
    const size_t n0 = (size_t)blockIdx.x * 32;
    if (t < 96) sq[t] = q[n0 * 3 + t];
    c[t] = cones[t];
    if (t < KC * CONE_STRIDE - 256) c[256 + t] = cones[256 + t];
    __syncthreads();
    const int nl = t >> 3;
    const int k0 = (t & 7) << 2;
    const float qx = sq[nl*3+0], qy = sq[nl*3+1], qz = sq[nl*3+2];
    float4 o;
    float* of = &o.x;
    #pragma unroll
    for (int kk = 0; kk < 4; ++kk) {
        const float* ck = &c[(k0 + kk) * CONE_STRIDE];
        const float vx = qx - ck[0];
        const float vy = qy - ck[1];
        const float vz = qz - ck[2];
        const float proj = vx*ck[3] + vy*ck[4] + vz*ck[5];
        const float d2 = vx*vx + vy*vy + vz*vz;
        float pp = d2 - proj * proj;
        pp = pp > 0.f ? pp : 0.f;
        const float perp = sqrtf(pp);
        const float slant = perp - ck[6] + ck[9] * proj;
        const float cap = fabsf(proj) - ck[7];
        of[kk] = slant > cap ? slant : cap;
    }
    *reinterpret_cast<float4*>(&out[(n0 + nl) * (size_t)KC + k0]) = o;
}

extern "C" void kernel_launch(void* const* d_in, const int* in_sizes, int n_in,
                              void* d_out, int out_size, void* d_ws, size_t ws_size,
                              hipStream_t stream) {
    const float* vox  = (const float*)d_in[0];
    const float* q    = (const float*)d_in[1];
    // d_in[2] = initial_centers: unused by the reference
    const float* Wenc = (const float*)d_in[3];
    const float* benc = (const float*)d_in[4];
    const float* Wdec = (const float*)d_in[5];
    const float* bdec = (const float*)d_in[6];
    const float* Wmap = (const float*)d_in[7];
    const float* bmap = (const float*)d_in[8];
    float* out = (float*)d_out;
    float* ws  = (float*)d_ws;

    const size_t PART_FLOATS = 512 * 512;   // 1 MB transposed partials
    const size_t need = (PART_FLOATS + 512 + 256 + KC * CONE_STRIDE) * sizeof(float);
    const int mode = (ws_size >= need) ? 1 : 0;

    float *dst, *decsum, *mapsum, *cones;
    if (mode) {
        dst    = ws;                 // partialT[512][512]
        decsum = ws + PART_FLOATS;
        mapsum = decsum + 512;
        cones  = mapsum + 256;
    } else {
        dst    = ws;                 // featsum[512]
        decsum = ws + 512;
        mapsum = ws + 1024;
        cones  = ws + 1280;
        hipMemsetAsync(dst, 0, 512 * sizeof(float), stream);  // featsum zero (atomic path)
    }

    k_enc<<<512, 512, 0, stream>>>(vox, Wenc, dst, decsum, mode);  // zbase = decsum..mapsum (768 floats)
    k_dec<<<128, 512, 0, stream>>>(dst, benc, Wdec, decsum, mode);
    k_map<<<64, 256, 0, stream>>>(decsum, bdec, Wmap, mapsum);
    k_params<<<1, 256, 0, stream>>>(mapsum, bmap, out + (size_t)NQ * KC, cones);
    k_sdf<<<NQ / 32, 256, 0, stream>>>(q, cones, out);
}